// Round 3
// baseline (353.876 us; speedup 1.0000x reference)
//
#include <hip/hip_runtime.h>
#include <hip/hip_bf16.h>
#include <stdint.h>
#include <stddef.h>

// ---------------------------------------------------------------------------
// FixedEmbedderNN — all-linear fold + transposed-MFMA pipeline.
//   WL_i   = W1[i]@W2[i];  bfold_i = b1[i]@W2[i]+b2[i]
//   Tcat1[f][c] = emb[f][c] @ W_in_f @ WL_0      (bf16, column-PERMUTED store)
//   A1[k][:]    = numeric fold rows (k=0..19), k=20 = const base (+bfold_0)
//   LN gamma/beta folded into downstream weights.
// Main kernel: wave = 16 rows, lane owns row c16 (4 lanes per row via g).
//   acc = mfma(A1^T, x)  +  20 gathered tcat rows (64B/lane, double-buffered
//   2-feature chunks to hide L2 latency)  -> LN0 -> GEMM2' -> LN1 -> GEMM3'.
// No block-level sync: x read directly per-lane; hbuf is per-wave private.
// ---------------------------------------------------------------------------

typedef __attribute__((ext_vector_type(8))) short short8;
typedef __attribute__((ext_vector_type(4))) float f32x4;
typedef __attribute__((ext_vector_type(2))) uint32_t uint32x2;

#define LN_EPS 1e-5f

__device__ __forceinline__ float bflo(uint32_t u){ union{uint32_t u;float f;} c; c.u = u<<16; return c.f; }
__device__ __forceinline__ float bfhi(uint32_t u){ union{uint32_t u;float f;} c; c.u = u&0xffff0000u; return c.f; }
__device__ __forceinline__ uint16_t f2bf(float f){
  union{ __hip_bfloat16 h; uint16_t u; } c; c.h = __float2bfloat16(f); return c.u;
}
__device__ __forceinline__ uint32_t pkbf(float lo, float hi){
  return (uint32_t)f2bf(lo) | ((uint32_t)f2bf(hi)<<16);
}

// ---------------- precompute kernel 1 (no deps) ----------------
__global__ __launch_bounds__(128) void pre1(
    const float* __restrict__ W_num, const float* __restrict__ b_num,
    const float* __restrict__ W_in,  const float* __restrict__ b_in,
    const float* __restrict__ W1,    const float* __restrict__ b1,
    const float* __restrict__ W2,    const float* __restrict__ b2,
    const float* __restrict__ W_out, const float* __restrict__ b_out,
    const float* __restrict__ ln_g,  const float* __restrict__ ln_b,
    float* __restrict__ WLf,    // [2][128][128]
    float* __restrict__ Bnum,   // [21][128]
    float* __restrict__ bfold,  // [2][128]
    uint16_t* __restrict__ woutp, // Wout' transposed pack [(t*4+ks)*64+lane][8]
    float* __restrict__ boutp)    // bout' permuted [g*32+t*4+r]
{
  const int b = blockIdx.x, j = threadIdx.x;
  if (b < 256) {                       // WL = W1@W2 per layer
    const int l = b >> 7, k = b & 127;
    const float* w1r = W1 + (l*128 + k)*256;
    const float* w2  = W2 + l*256*128;
    float s = 0.f;
    for (int m = 0; m < 256; m++) s = fmaf(w1r[m], w2[m*128 + j], s);
    WLf[(l*128 + k)*128 + j] = s;
  } else if (b < 277) {                // Bnum rows
    const int r = b - 256;
    if (r < 20) {
      const float* wn = W_num + r*32;
      const float* wi = W_in + (size_t)(20 + r)*32*128;
      float s = 0.f;
      for (int e = 0; e < 32; e++) s = fmaf(wn[e], wi[e*128 + j], s);
      Bnum[r*128 + j] = s;
    } else {
      float s = b_in[j];
      for (int f = 0; f < 20; f++) {
        const float* bn = b_num + f*32;
        const float* wi = W_in + (size_t)(20 + f)*32*128;
        for (int e = 0; e < 32; e++) s = fmaf(bn[e], wi[e*128 + j], s);
      }
      Bnum[20*128 + j] = s;
    }
  } else if (b < 279) {                // bfold = b1@W2 + b2
    const int l = b - 277;
    const float* b1r = b1 + l*256;
    const float* w2  = W2 + l*256*128;
    float s = b2[l*128 + j];
    for (int k = 0; k < 256; k++) s = fmaf(b1r[k], w2[k*128 + j], s);
    bfold[l*128 + j] = s;
  } else if (b < 311) {                // woutp: Wout' = diag(g1)@W_out, transposed A-pack
    const int p = b - 279, t = p >> 2, ks = p & 3;
    const int lane = j & 63, rep = j >> 6;
    const int col = 16*t + (lane & 15);
    for (int ii = 0; ii < 4; ii++) {
      const int i = rep*4 + ii;
      const int k = 32*ks + 8*(lane >> 4) + i;
      woutp[((t*4 + ks)*64 + lane)*8 + i] = f2bf(ln_g[128 + k] * W_out[k*128 + col]);
    }
  } else {                             // boutp (permuted): b1n@W_out + b_out
    const int t = (j >> 2) & 7, g = j >> 5, r = j & 3;
    const int col = 16*t + 4*g + r;
    float s = b_out[col];
    for (int k = 0; k < 128; k++) s = fmaf(ln_b[128 + k], W_out[k*128 + col], s);
    boutp[j] = s;
  }
}

// ---------------- precompute kernel 2 (depends on pre1) ----------------
__global__ __launch_bounds__(128) void pre2(
    const float* __restrict__ emb, const float* __restrict__ W_in,
    const float* __restrict__ ln_g, const float* __restrict__ ln_b,
    const float* __restrict__ WLf, const float* __restrict__ Bnum,
    const float* __restrict__ bfold,
    uint16_t* __restrict__ tcatp, // [20][50][128] bf16, columns permuted g*32+t*4+r <- 16t+4g+r
    uint16_t* __restrict__ wl2p,  // WL1' transposed pack
    float* __restrict__ bf1p,     // bf1' permuted
    uint16_t* __restrict__ a1p)   // A1^T A-frag pack [t*64+lane][8]
{
  const int b = blockIdx.x, j = threadIdx.x;
  __shared__ float sh[128];
  if (b < 1000) {                      // Tcat1 = emb@W_in_slice@WL_0, permuted store
    const int f = b / 50, c = b % 50;
    const float* e  = emb + (f*50 + c)*32;
    const float* wi = W_in + (size_t)f*32*128;
    float s = 0.f;
    for (int k = 0; k < 32; k++) s = fmaf(e[k], wi[k*128 + j], s);
    sh[j] = s;
    __syncthreads();
    float s2 = 0.f;
    for (int k = 0; k < 128; k++) s2 = fmaf(sh[k], WLf[k*128 + j], s2);
    const int t = j >> 4, g = (j >> 2) & 3, r = j & 3;   // j = 16t+4g+r
    tcatp[(f*50 + c)*128 + g*32 + t*4 + r] = f2bf(s2);
  } else if (b < 1032) {               // wl2p: WL1' = diag(g0)@WL_1, transposed A-pack
    const int p = b - 1000, t = p >> 2, ks = p & 3;
    const int lane = j & 63, rep = j >> 6;
    const int col = 16*t + (lane & 15);
    const float* wl1 = WLf + 16384;
    for (int ii = 0; ii < 4; ii++) {
      const int i = rep*4 + ii;
      const int k = 32*ks + 8*(lane >> 4) + i;
      wl2p[((t*4 + ks)*64 + lane)*8 + i] = f2bf(ln_g[k] * wl1[k*128 + col]);
    }
  } else if (b == 1032) {              // bf1p (permuted): b0@WL_1 + bfold_1
    const int t = (j >> 2) & 7, g = j >> 5, r = j & 3;
    const int col = 16*t + 4*g + r;
    const float* wl1 = WLf + 16384;
    float s = bfold[128 + col];
    for (int k = 0; k < 128; k++) s = fmaf(ln_b[k], wl1[k*128 + col], s);
    bf1p[j] = s;
  } else {                             // a1p: A1[k][col] = Bnum[k]@WL_0 (+bfold0 @k==20)
    const int t = b - 1033;
    const int lane = j & 63, rep = j >> 6;
    const int col = 16*t + (lane & 15);
    for (int ii = 0; ii < 4; ii++) {
      const int i = rep*4 + ii;
      const int k = 8*(lane >> 4) + i;
      float v = 0.f;
      if (k <= 20) {
        if (k == 20) v = bfold[col];
        for (int m = 0; m < 128; m++) v = fmaf(Bnum[k*128 + m], WLf[m*128 + col], v);
      }
      a1p[(t*64 + lane)*8 + i] = f2bf(v);
    }
  }
}

// ---------------- main fused kernel ----------------
// block = 256 thr (4 waves); wave owns 16 rows; block tile = 64 rows.
// No __syncthreads: per-lane x loads, per-wave-private hbuf.
__global__ __launch_bounds__(256, 4) void fused_main(
    const float* __restrict__ x,
    const uint16_t* __restrict__ tcatp,
    const uint16_t* __restrict__ a1p,
    const uint16_t* __restrict__ wl2p,
    const uint16_t* __restrict__ woutp,
    const float* __restrict__ bf1p,
    const float* __restrict__ boutp,
    float* __restrict__ out)
{
  __shared__ __align__(16) uint16_t hbuf[4*16*136];  // per-wave 16x128 bf16, stride 136
  const int tid = threadIdx.x, lane = tid & 63, w = tid >> 6;
  const int g = lane >> 4, c16 = lane & 15;
  const int row = blockIdx.x*64 + w*16 + c16;
  const float* xrow = x + (size_t)row*40;
  uint16_t* hb = hbuf + w*16*136;

  // ---- 20 gather byte-offsets from categorical codes (4 dup lanes coalesce) ----
  uint32_t off[20];
  {
    const f32x4 i0 = *reinterpret_cast<const f32x4*>(xrow);
    const f32x4 i1 = *reinterpret_cast<const f32x4*>(xrow + 4);
    const f32x4 i2 = *reinterpret_cast<const f32x4*>(xrow + 8);
    const f32x4 i3 = *reinterpret_cast<const f32x4*>(xrow + 12);
    const f32x4 i4 = *reinterpret_cast<const f32x4*>(xrow + 16);
    const uint32_t gb = (uint32_t)g * 64u;
    #pragma unroll
    for (int k = 0; k < 4; k++) {
      off[k]      = (uint32_t)i0[k]*256u + (uint32_t)(k)*12800u      + gb;
      off[4 + k]  = (uint32_t)i1[k]*256u + (uint32_t)(4 + k)*12800u  + gb;
      off[8 + k]  = (uint32_t)i2[k]*256u + (uint32_t)(8 + k)*12800u  + gb;
      off[12 + k] = (uint32_t)i3[k]*256u + (uint32_t)(12 + k)*12800u + gb;
      off[16 + k] = (uint32_t)i4[k]*256u + (uint32_t)(16 + k)*12800u + gb;
    }
  }

  const char* tcb = (const char*)tcatp;
  uint4 bA[8], bB[8];
#define LOADC(B, f0) { \
    const char* p0 = tcb + off[f0]; const char* p1 = tcb + off[(f0) + 1]; \
    B[0] = *(const uint4*)(p0);      B[1] = *(const uint4*)(p0 + 16); \
    B[2] = *(const uint4*)(p0 + 32); B[3] = *(const uint4*)(p0 + 48); \
    B[4] = *(const uint4*)(p1);      B[5] = *(const uint4*)(p1 + 16); \
    B[6] = *(const uint4*)(p1 + 32); B[7] = *(const uint4*)(p1 + 48); }

#define CONS(B) { \
    _Pragma("unroll") \
    for (int j = 0; j < 8; j++) { const int q = j & 3; \
      const uint32_t w0 = B[j].x, w1 = B[j].y, w2 = B[j].z, w3 = B[j].w; \
      acc[2*q][0]   += bflo(w0); acc[2*q][1]   += bfhi(w0); \
      acc[2*q][2]   += bflo(w1); acc[2*q][3]   += bfhi(w1); \
      acc[2*q+1][0] += bflo(w2); acc[2*q+1][1] += bfhi(w2); \
      acc[2*q+1][2] += bflo(w3); acc[2*q+1][3] += bfhi(w3); } }

  LOADC(bA, 0);                      // first chunk in flight

  // ---- numeric part via MFMA (overlaps first gather latency) ----
  float nv[8] = {0.f,0.f,0.f,0.f,0.f,0.f,0.f,0.f};
  if (g == 0) {
    const f32x4 a = *reinterpret_cast<const f32x4*>(xrow + 20);
    const f32x4 b = *reinterpret_cast<const f32x4*>(xrow + 24);
    nv[0]=a[0]; nv[1]=a[1]; nv[2]=a[2]; nv[3]=a[3];
    nv[4]=b[0]; nv[5]=b[1]; nv[6]=b[2]; nv[7]=b[3];
  } else if (g == 1) {
    const f32x4 a = *reinterpret_cast<const f32x4*>(xrow + 28);
    const f32x4 b = *reinterpret_cast<const f32x4*>(xrow + 32);
    nv[0]=a[0]; nv[1]=a[1]; nv[2]=a[2]; nv[3]=a[3];
    nv[4]=b[0]; nv[5]=b[1]; nv[6]=b[2]; nv[7]=b[3];
  } else if (g == 2) {
    const f32x4 a = *reinterpret_cast<const f32x4*>(xrow + 36);
    nv[0]=a[0]; nv[1]=a[1]; nv[2]=a[2]; nv[3]=a[3];
    nv[4]=1.0f;
  }                                   // g==3: all zero (A1 rows k>20 are zero)
  short8 xf;
  #pragma unroll
  for (int i = 0; i < 8; i++) ((uint16_t*)&xf)[i] = f2bf(nv[i]);

  f32x4 acc[8];
  #pragma unroll
  for (int t = 0; t < 8; t++) {
    const short8 af = *reinterpret_cast<const short8*>(a1p + (t*64 + lane)*8);
    acc[t] = __builtin_amdgcn_mfma_f32_16x16x32_bf16(af, xf, (f32x4){0.f,0.f,0.f,0.f}, 0, 0, 0);
  }

  // ---- double-buffered gather: 2 features/chunk, 16 loads in flight ----
  LOADC(bB, 2);  CONS(bA);
  LOADC(bA, 4);  CONS(bB);
  LOADC(bB, 6);  CONS(bA);
  LOADC(bA, 8);  CONS(bB);
  LOADC(bB, 10); CONS(bA);
  LOADC(bA, 12); CONS(bB);
  LOADC(bB, 14); CONS(bA);
  LOADC(bA, 16); CONS(bB);
  LOADC(bB, 18); CONS(bA);
  CONS(bB);

  // ---- LN_0 (gamma/beta folded downstream): z1 = (acc-mu)*rs ----
  float s = 0.f;
  #pragma unroll
  for (int t = 0; t < 8; t++) { s += acc[t][0]+acc[t][1]+acc[t][2]+acc[t][3]; }
  s += __shfl_xor(s, 16); s += __shfl_xor(s, 32);
  const float mu = s * (1.f/128.f);
  float qv = 0.f;
  #pragma unroll
  for (int t = 0; t < 8; t++)
    #pragma unroll
    for (int r = 0; r < 4; r++) { const float d = acc[t][r]-mu; qv = fmaf(d, d, qv); }
  qv += __shfl_xor(qv, 16); qv += __shfl_xor(qv, 32);
  const float rs = rsqrtf(qv*(1.f/128.f) + LN_EPS);

  #pragma unroll
  for (int t = 0; t < 8; t++) {
    const uint32x2 v = { pkbf((acc[t][0]-mu)*rs, (acc[t][1]-mu)*rs),
                         pkbf((acc[t][2]-mu)*rs, (acc[t][3]-mu)*rs) };
    *reinterpret_cast<uint32x2*>(hb + c16*136 + 16*t + 4*g) = v;
  }
  asm volatile("s_waitcnt lgkmcnt(0)" ::: "memory");

  // ---- GEMM2' (transposed): acc2 = z1 @ WL1' ----
  short8 a2[4];
  #pragma unroll
  for (int ks = 0; ks < 4; ks++)
    a2[ks] = *reinterpret_cast<const short8*>(hb + c16*136 + 32*ks + 8*g);
  f32x4 acc2[8];
  #pragma unroll
  for (int t = 0; t < 8; t++) {
    acc2[t] = *reinterpret_cast<const f32x4*>(bf1p + g*32 + t*4);  // bias as C-init
    #pragma unroll
    for (int ks = 0; ks < 4; ks++) {
      const short8 wf = *reinterpret_cast<const short8*>(wl2p + ((t*4 + ks)*64 + lane)*8);
      acc2[t] = __builtin_amdgcn_mfma_f32_16x16x32_bf16(wf, a2[ks], acc2[t], 0, 0, 0);
    }
  }

  // ---- LN_1: z2 = (acc2-mu2)*rs2 ----
  float s2 = 0.f;
  #pragma unroll
  for (int t = 0; t < 8; t++) { s2 += acc2[t][0]+acc2[t][1]+acc2[t][2]+acc2[t][3]; }
  s2 += __shfl_xor(s2, 16); s2 += __shfl_xor(s2, 32);
  const float mu2 = s2 * (1.f/128.f);
  float q2 = 0.f;
  #pragma unroll
  for (int t = 0; t < 8; t++)
    #pragma unroll
    for (int r = 0; r < 4; r++) { const float d = acc2[t][r]-mu2; q2 = fmaf(d, d, q2); }
  q2 += __shfl_xor(q2, 16); q2 += __shfl_xor(q2, 32);
  const float rs2 = rsqrtf(q2*(1.f/128.f) + LN_EPS);

  asm volatile("s_waitcnt lgkmcnt(0)" ::: "memory");   // a2 reads done before overwrite
  #pragma unroll
  for (int t = 0; t < 8; t++) {
    const uint32x2 v = { pkbf((acc2[t][0]-mu2)*rs2, (acc2[t][1]-mu2)*rs2),
                         pkbf((acc2[t][2]-mu2)*rs2, (acc2[t][3]-mu2)*rs2) };
    *reinterpret_cast<uint32x2*>(hb + c16*136 + 16*t + 4*g) = v;
  }
  asm volatile("s_waitcnt lgkmcnt(0)" ::: "memory");

  // ---- GEMM3' (transposed): out = z2 @ Wout' + bout' ----
  short8 a3[4];
  #pragma unroll
  for (int ks = 0; ks < 4; ks++)
    a3[ks] = *reinterpret_cast<const short8*>(hb + c16*136 + 32*ks + 8*g);
  const size_t orow = ((size_t)blockIdx.x*64 + w*16 + c16)*128;
  #pragma unroll
  for (int t = 0; t < 8; t++) {
    f32x4 a3c = *reinterpret_cast<const f32x4*>(boutp + g*32 + t*4);  // bias as C-init
    #pragma unroll
    for (int ks = 0; ks < 4; ks++) {
      const short8 wf = *reinterpret_cast<const short8*>(woutp + ((t*4 + ks)*64 + lane)*8);
      a3c = __builtin_amdgcn_mfma_f32_16x16x32_bf16(wf, a3[ks], a3c, 0, 0, 0);
    }
    __builtin_nontemporal_store(a3c, reinterpret_cast<f32x4*>(out + orow + 16*t + 4*g));
  }
}

// ---------------- launcher ----------------
extern "C" void kernel_launch(void* const* d_in, const int* in_sizes, int n_in,
                              void* d_out, int out_size, void* d_ws, size_t ws_size,
                              hipStream_t stream)
{
  const float* x     = (const float*)d_in[0];
  const float* emb   = (const float*)d_in[1];
  const float* W_num = (const float*)d_in[2];
  const float* b_num = (const float*)d_in[3];
  const float* W_in  = (const float*)d_in[4];
  const float* b_in  = (const float*)d_in[5];
  const float* W1    = (const float*)d_in[6];
  const float* b1    = (const float*)d_in[7];
  const float* W2    = (const float*)d_in[8];
  const float* b2    = (const float*)d_in[9];
  const float* ln_g  = (const float*)d_in[10];
  const float* ln_b  = (const float*)d_in[11];
  const float* W_out = (const float*)d_in[12];
  const float* b_out = (const float*)d_in[13];
  float* out = (float*)d_out;

  char* ws = (char*)d_ws;
  float*    WLf   = (float*)(ws + 0);         // 131072 B
  float*    Bnum  = (float*)(ws + 131072);    //  10752 B
  float*    bfold = (float*)(ws + 141824);    //   1024 B
  uint16_t* tcatp = (uint16_t*)(ws + 142848); // 256000 B
  uint16_t* wl2p  = (uint16_t*)(ws + 398848); //  32768 B
  uint16_t* woutp = (uint16_t*)(ws + 431616); //  32768 B
  uint16_t* a1p   = (uint16_t*)(ws + 464384); //   8192 B
  float*    bf1p  = (float*)(ws + 472576);    //    512 B
  float*    boutp = (float*)(ws + 473088);    //    512 B

  const int nrows = in_sizes[0] / 40;         // 98304
  const int grid  = nrows / 64;               // 1536

  pre1<<<dim3(312), dim3(128), 0, stream>>>(W_num, b_num, W_in, b_in, W1, b1, W2, b2,
                                            W_out, b_out, ln_g, ln_b,
                                            WLf, Bnum, bfold, woutp, boutp);
  pre2<<<dim3(1041), dim3(128), 0, stream>>>(emb, W_in, ln_g, ln_b, WLf, Bnum, bfold,
                                             tcatp, wl2p, bf1p, a1p);
  fused_main<<<dim3(grid), dim3(256), 0, stream>>>(x, tcatp, a1p, wl2p, woutp,
                                                   bf1p, boutp, out);
}

// Round 4
// 301.517 us; speedup vs baseline: 1.1737x; 1.1737x over previous
//
#include <hip/hip_runtime.h>
#include <hip/hip_bf16.h>
#include <stdint.h>
#include <stddef.h>

// ---------------------------------------------------------------------------
// FixedEmbedderNN — all-linear fold + transposed-MFMA pipeline.
//   WL_i   = W1[i]@W2[i];  bfold_i = b1[i]@W2[i]+b2[i]
//   Tcat1[f][c] = emb[f][c] @ W_in_f @ WL_0      (bf16, column-PERMUTED store)
//   A1[k][:]    = numeric fold rows (k=0..19), k=20 = const base (+bfold_0)
//   LN gamma/beta folded into downstream weights.
// Gather layout (line-optimal): the 4 lanes (g=0..3) of a row read ONE
// contiguous 64B line per instruction (lane off = g*16, instr q steps +64B),
// so each instr touches 16 lines fully-consumed (was: 64 lines re-touched 4x).
// Column permutation: col c=16t+4g+r stored at pos = (t>>1)*32 + g*8 + (t&1)*4 + r.
// ---------------------------------------------------------------------------

typedef __attribute__((ext_vector_type(8))) short short8;
typedef __attribute__((ext_vector_type(4))) float f32x4;
typedef __attribute__((ext_vector_type(2))) uint32_t uint32x2;

#define LN_EPS 1e-5f

__device__ __forceinline__ float bflo(uint32_t u){ union{uint32_t u;float f;} c; c.u = u<<16; return c.f; }
__device__ __forceinline__ float bfhi(uint32_t u){ union{uint32_t u;float f;} c; c.u = u&0xffff0000u; return c.f; }
__device__ __forceinline__ uint16_t f2bf(float f){
  union{ __hip_bfloat16 h; uint16_t u; } c; c.h = __float2bfloat16(f); return c.u;
}
__device__ __forceinline__ uint32_t pkbf(float lo, float hi){
  return (uint32_t)f2bf(lo) | ((uint32_t)f2bf(hi)<<16);
}

// ---------------- precompute kernel 1 (no deps) ----------------
__global__ __launch_bounds__(128) void pre1(
    const float* __restrict__ W_num, const float* __restrict__ b_num,
    const float* __restrict__ W_in,  const float* __restrict__ b_in,
    const float* __restrict__ W1,    const float* __restrict__ b1,
    const float* __restrict__ W2,    const float* __restrict__ b2,
    const float* __restrict__ W_out, const float* __restrict__ b_out,
    const float* __restrict__ ln_g,  const float* __restrict__ ln_b,
    float* __restrict__ WLf,    // [2][128][128]
    float* __restrict__ Bnum,   // [21][128]
    float* __restrict__ bfold,  // [2][128]
    uint16_t* __restrict__ woutp, // Wout' transposed pack [(t*4+ks)*64+lane][8]
    float* __restrict__ boutp)    // bout' permuted [g*32+t*4+r]
{
  const int b = blockIdx.x, j = threadIdx.x;
  if (b < 256) {                       // WL = W1@W2 per layer
    const int l = b >> 7, k = b & 127;
    const float* w1r = W1 + (l*128 + k)*256;
    const float* w2  = W2 + l*256*128;
    float s = 0.f;
    for (int m = 0; m < 256; m++) s = fmaf(w1r[m], w2[m*128 + j], s);
    WLf[(l*128 + k)*128 + j] = s;
  } else if (b < 277) {                // Bnum rows
    const int r = b - 256;
    if (r < 20) {
      const float* wn = W_num + r*32;
      const float* wi = W_in + (size_t)(20 + r)*32*128;
      float s = 0.f;
      for (int e = 0; e < 32; e++) s = fmaf(wn[e], wi[e*128 + j], s);
      Bnum[r*128 + j] = s;
    } else {
      float s = b_in[j];
      for (int f = 0; f < 20; f++) {
        const float* bn = b_num + f*32;
        const float* wi = W_in + (size_t)(20 + f)*32*128;
        for (int e = 0; e < 32; e++) s = fmaf(bn[e], wi[e*128 + j], s);
      }
      Bnum[20*128 + j] = s;
    }
  } else if (b < 279) {                // bfold = b1@W2 + b2
    const int l = b - 277;
    const float* b1r = b1 + l*256;
    const float* w2  = W2 + l*256*128;
    float s = b2[l*128 + j];
    for (int k = 0; k < 256; k++) s = fmaf(b1r[k], w2[k*128 + j], s);
    bfold[l*128 + j] = s;
  } else if (b < 311) {                // woutp: Wout' = diag(g1)@W_out, transposed A-pack
    const int p = b - 279, t = p >> 2, ks = p & 3;
    const int lane = j & 63, rep = j >> 6;
    const int col = 16*t + (lane & 15);
    for (int ii = 0; ii < 4; ii++) {
      const int i = rep*4 + ii;
      const int k = 32*ks + 8*(lane >> 4) + i;
      woutp[((t*4 + ks)*64 + lane)*8 + i] = f2bf(ln_g[128 + k] * W_out[k*128 + col]);
    }
  } else {                             // boutp (permuted): b1n@W_out + b_out
    const int t = (j >> 2) & 7, g = j >> 5, r = j & 3;
    const int col = 16*t + 4*g + r;
    float s = b_out[col];
    for (int k = 0; k < 128; k++) s = fmaf(ln_b[128 + k], W_out[k*128 + col], s);
    boutp[j] = s;
  }
}

// ---------------- precompute kernel 2 (depends on pre1) ----------------
__global__ __launch_bounds__(128) void pre2(
    const float* __restrict__ emb, const float* __restrict__ W_in,
    const float* __restrict__ ln_g, const float* __restrict__ ln_b,
    const float* __restrict__ WLf, const float* __restrict__ Bnum,
    const float* __restrict__ bfold,
    uint16_t* __restrict__ tcatp, // [20][50][128] bf16, line-optimal permuted cols
    uint16_t* __restrict__ wl2p,  // WL1' transposed pack
    float* __restrict__ bf1p,     // bf1' permuted
    uint16_t* __restrict__ a1p)   // A1^T A-frag pack [t*64+lane][8]
{
  const int b = blockIdx.x, j = threadIdx.x;
  __shared__ float sh[128];
  if (b < 1000) {                      // Tcat1 = emb@W_in_slice@WL_0, permuted store
    const int f = b / 50, c = b % 50;
    const float* e  = emb + (f*50 + c)*32;
    const float* wi = W_in + (size_t)f*32*128;
    float s = 0.f;
    for (int k = 0; k < 32; k++) s = fmaf(e[k], wi[k*128 + j], s);
    sh[j] = s;
    __syncthreads();
    float s2 = 0.f;
    for (int k = 0; k < 128; k++) s2 = fmaf(sh[k], WLf[k*128 + j], s2);
    // col j = 16t+4g+r  ->  pos = (t>>1)*32 + g*8 + (t&1)*4 + r
    const int t = j >> 4, g = (j >> 2) & 3, r = j & 3;
    const int pos = ((t >> 1) << 5) | (g << 3) | ((t & 1) << 2) | r;
    tcatp[(f*50 + c)*128 + pos] = f2bf(s2);
  } else if (b < 1032) {               // wl2p: WL1' = diag(g0)@WL_1, transposed A-pack
    const int p = b - 1000, t = p >> 2, ks = p & 3;
    const int lane = j & 63, rep = j >> 6;
    const int col = 16*t + (lane & 15);
    const float* wl1 = WLf + 16384;
    for (int ii = 0; ii < 4; ii++) {
      const int i = rep*4 + ii;
      const int k = 32*ks + 8*(lane >> 4) + i;
      wl2p[((t*4 + ks)*64 + lane)*8 + i] = f2bf(ln_g[k] * wl1[k*128 + col]);
    }
  } else if (b == 1032) {              // bf1p (permuted): b0@WL_1 + bfold_1
    const int t = (j >> 2) & 7, g = j >> 5, r = j & 3;
    const int col = 16*t + 4*g + r;
    const float* wl1 = WLf + 16384;
    float s = bfold[128 + col];
    for (int k = 0; k < 128; k++) s = fmaf(ln_b[k], wl1[k*128 + col], s);
    bf1p[j] = s;
  } else {                             // a1p: A1[k][col] = Bnum[k]@WL_0 (+bfold0 @k==20)
    const int t = b - 1033;
    const int lane = j & 63, rep = j >> 6;
    const int col = 16*t + (lane & 15);
    for (int ii = 0; ii < 4; ii++) {
      const int i = rep*4 + ii;
      const int k = 8*(lane >> 4) + i;
      float v = 0.f;
      if (k <= 20) {
        if (k == 20) v = bfold[col];
        for (int m = 0; m < 128; m++) v = fmaf(Bnum[k*128 + m], WLf[m*128 + col], v);
      }
      a1p[(t*64 + lane)*8 + i] = f2bf(v);
    }
  }
}

// ---------------- main fused kernel ----------------
// block = 256 thr (4 waves); wave owns 16 rows; block tile = 64 rows.
// No __syncthreads: per-lane x loads, per-wave-private hbuf.
__global__ __launch_bounds__(256, 4) void fused_main(
    const float* __restrict__ x,
    const uint16_t* __restrict__ tcatp,
    const uint16_t* __restrict__ a1p,
    const uint16_t* __restrict__ wl2p,
    const uint16_t* __restrict__ woutp,
    const float* __restrict__ bf1p,
    const float* __restrict__ boutp,
    float* __restrict__ out)
{
  __shared__ __align__(16) uint16_t hbuf[4*16*136];  // per-wave 16x128 bf16, stride 136
  const int tid = threadIdx.x, lane = tid & 63, w = tid >> 6;
  const int g = lane >> 4, c16 = lane & 15;
  const int row = blockIdx.x*64 + w*16 + c16;
  const float* xrow = x + (size_t)row*40;
  uint16_t* hb = hbuf + w*16*136;

  // ---- 20 gather byte-offsets from categorical codes (4 dup lanes coalesce) ----
  uint32_t off[20];
  {
    const f32x4 i0 = *reinterpret_cast<const f32x4*>(xrow);
    const f32x4 i1 = *reinterpret_cast<const f32x4*>(xrow + 4);
    const f32x4 i2 = *reinterpret_cast<const f32x4*>(xrow + 8);
    const f32x4 i3 = *reinterpret_cast<const f32x4*>(xrow + 12);
    const f32x4 i4 = *reinterpret_cast<const f32x4*>(xrow + 16);
    const uint32_t gb = (uint32_t)g * 16u;           // lane slice WITHIN a 64B line
    #pragma unroll
    for (int k = 0; k < 4; k++) {
      off[k]      = (uint32_t)i0[k]*256u + (uint32_t)(k)*12800u      + gb;
      off[4 + k]  = (uint32_t)i1[k]*256u + (uint32_t)(4 + k)*12800u  + gb;
      off[8 + k]  = (uint32_t)i2[k]*256u + (uint32_t)(8 + k)*12800u  + gb;
      off[12 + k] = (uint32_t)i3[k]*256u + (uint32_t)(12 + k)*12800u + gb;
      off[16 + k] = (uint32_t)i4[k]*256u + (uint32_t)(16 + k)*12800u + gb;
    }
  }

  const char* tcb = (const char*)tcatp;
  uint4 bA[4], bB[4];
#define LOADC1(B, f) { \
    const char* p = tcb + off[f]; \
    B[0] = *(const uint4*)(p);       B[1] = *(const uint4*)(p + 64); \
    B[2] = *(const uint4*)(p + 128); B[3] = *(const uint4*)(p + 192); }

  // elem (q, j): t = 2q + (j>>2), r = j&3  (matches pre2's permutation)
#define CONS1(B) { \
    _Pragma("unroll") \
    for (int q = 0; q < 4; q++) { \
      const uint32_t w0 = B[q].x, w1 = B[q].y, w2 = B[q].z, w3 = B[q].w; \
      acc[2*q][0]   += bflo(w0); acc[2*q][1]   += bfhi(w0); \
      acc[2*q][2]   += bflo(w1); acc[2*q][3]   += bfhi(w1); \
      acc[2*q+1][0] += bflo(w2); acc[2*q+1][1] += bfhi(w2); \
      acc[2*q+1][2] += bflo(w3); acc[2*q+1][3] += bfhi(w3); } }

  LOADC1(bA, 0);                     // first chunk in flight

  // ---- numeric part via MFMA (overlaps first gather latency) ----
  float nv[8] = {0.f,0.f,0.f,0.f,0.f,0.f,0.f,0.f};
  if (g == 0) {
    const f32x4 a = *reinterpret_cast<const f32x4*>(xrow + 20);
    const f32x4 b = *reinterpret_cast<const f32x4*>(xrow + 24);
    nv[0]=a[0]; nv[1]=a[1]; nv[2]=a[2]; nv[3]=a[3];
    nv[4]=b[0]; nv[5]=b[1]; nv[6]=b[2]; nv[7]=b[3];
  } else if (g == 1) {
    const f32x4 a = *reinterpret_cast<const f32x4*>(xrow + 28);
    const f32x4 b = *reinterpret_cast<const f32x4*>(xrow + 32);
    nv[0]=a[0]; nv[1]=a[1]; nv[2]=a[2]; nv[3]=a[3];
    nv[4]=b[0]; nv[5]=b[1]; nv[6]=b[2]; nv[7]=b[3];
  } else if (g == 2) {
    const f32x4 a = *reinterpret_cast<const f32x4*>(xrow + 36);
    nv[0]=a[0]; nv[1]=a[1]; nv[2]=a[2]; nv[3]=a[3];
    nv[4]=1.0f;
  }                                   // g==3: all zero (A1 rows k>20 are zero)
  short8 xf;
  #pragma unroll
  for (int i = 0; i < 8; i++) ((uint16_t*)&xf)[i] = f2bf(nv[i]);

  f32x4 acc[8];
  #pragma unroll
  for (int t = 0; t < 8; t++) {
    const short8 af = *reinterpret_cast<const short8*>(a1p + (t*64 + lane)*8);
    acc[t] = __builtin_amdgcn_mfma_f32_16x16x32_bf16(af, xf, (f32x4){0.f,0.f,0.f,0.f}, 0, 0, 0);
  }

  // ---- double-buffered gather: 1 feature/buffer, 2 in flight ----
  LOADC1(bB, 1);
  CONS1(bA); LOADC1(bA, 2);
  CONS1(bB); LOADC1(bB, 3);
  CONS1(bA); LOADC1(bA, 4);
  CONS1(bB); LOADC1(bB, 5);
  CONS1(bA); LOADC1(bA, 6);
  CONS1(bB); LOADC1(bB, 7);
  CONS1(bA); LOADC1(bA, 8);
  CONS1(bB); LOADC1(bB, 9);
  CONS1(bA); LOADC1(bA, 10);
  CONS1(bB); LOADC1(bB, 11);
  CONS1(bA); LOADC1(bA, 12);
  CONS1(bB); LOADC1(bB, 13);
  CONS1(bA); LOADC1(bA, 14);
  CONS1(bB); LOADC1(bB, 15);
  CONS1(bA); LOADC1(bA, 16);
  CONS1(bB); LOADC1(bB, 17);
  CONS1(bA); LOADC1(bA, 18);
  CONS1(bB); LOADC1(bB, 19);
  CONS1(bA);
  CONS1(bB);

  // ---- LN_0 (gamma/beta folded downstream): z1 = (acc-mu)*rs ----
  float s = 0.f;
  #pragma unroll
  for (int t = 0; t < 8; t++) { s += acc[t][0]+acc[t][1]+acc[t][2]+acc[t][3]; }
  s += __shfl_xor(s, 16); s += __shfl_xor(s, 32);
  const float mu = s * (1.f/128.f);
  float qv = 0.f;
  #pragma unroll
  for (int t = 0; t < 8; t++)
    #pragma unroll
    for (int r = 0; r < 4; r++) { const float d = acc[t][r]-mu; qv = fmaf(d, d, qv); }
  qv += __shfl_xor(qv, 16); qv += __shfl_xor(qv, 32);
  const float rs = rsqrtf(qv*(1.f/128.f) + LN_EPS);

  #pragma unroll
  for (int t = 0; t < 8; t++) {
    const uint32x2 v = { pkbf((acc[t][0]-mu)*rs, (acc[t][1]-mu)*rs),
                         pkbf((acc[t][2]-mu)*rs, (acc[t][3]-mu)*rs) };
    *reinterpret_cast<uint32x2*>(hb + c16*136 + 16*t + 4*g) = v;
  }
  asm volatile("s_waitcnt lgkmcnt(0)" ::: "memory");

  // ---- GEMM2' (transposed): acc2 = z1 @ WL1' ----
  short8 a2[4];
  #pragma unroll
  for (int ks = 0; ks < 4; ks++)
    a2[ks] = *reinterpret_cast<const short8*>(hb + c16*136 + 32*ks + 8*g);
  f32x4 acc2[8];
  #pragma unroll
  for (int t = 0; t < 8; t++) {
    acc2[t] = *reinterpret_cast<const f32x4*>(bf1p + g*32 + t*4);  // bias as C-init
    #pragma unroll
    for (int ks = 0; ks < 4; ks++) {
      const short8 wf = *reinterpret_cast<const short8*>(wl2p + ((t*4 + ks)*64 + lane)*8);
      acc2[t] = __builtin_amdgcn_mfma_f32_16x16x32_bf16(wf, a2[ks], acc2[t], 0, 0, 0);
    }
  }

  // ---- LN_1: z2 = (acc2-mu2)*rs2 ----
  float s2 = 0.f;
  #pragma unroll
  for (int t = 0; t < 8; t++) { s2 += acc2[t][0]+acc2[t][1]+acc2[t][2]+acc2[t][3]; }
  s2 += __shfl_xor(s2, 16); s2 += __shfl_xor(s2, 32);
  const float mu2 = s2 * (1.f/128.f);
  float q2 = 0.f;
  #pragma unroll
  for (int t = 0; t < 8; t++)
    #pragma unroll
    for (int r = 0; r < 4; r++) { const float d = acc2[t][r]-mu2; q2 = fmaf(d, d, q2); }
  q2 += __shfl_xor(q2, 16); q2 += __shfl_xor(q2, 32);
  const float rs2 = rsqrtf(q2*(1.f/128.f) + LN_EPS);

  asm volatile("s_waitcnt lgkmcnt(0)" ::: "memory");   // a2 reads done before overwrite
  #pragma unroll
  for (int t = 0; t < 8; t++) {
    const uint32x2 v = { pkbf((acc2[t][0]-mu2)*rs2, (acc2[t][1]-mu2)*rs2),
                         pkbf((acc2[t][2]-mu2)*rs2, (acc2[t][3]-mu2)*rs2) };
    *reinterpret_cast<uint32x2*>(hb + c16*136 + 16*t + 4*g) = v;
  }
  asm volatile("s_waitcnt lgkmcnt(0)" ::: "memory");

  // ---- GEMM3' (transposed): out = z2 @ Wout' + bout' ----
  short8 a3[4];
  #pragma unroll
  for (int ks = 0; ks < 4; ks++)
    a3[ks] = *reinterpret_cast<const short8*>(hb + c16*136 + 32*ks + 8*g);
  const size_t orow = ((size_t)blockIdx.x*64 + w*16 + c16)*128;
  #pragma unroll
  for (int t = 0; t < 8; t++) {
    f32x4 a3c = *reinterpret_cast<const f32x4*>(boutp + g*32 + t*4);  // bias as C-init
    #pragma unroll
    for (int ks = 0; ks < 4; ks++) {
      const short8 wf = *reinterpret_cast<const short8*>(woutp + ((t*4 + ks)*64 + lane)*8);
      a3c = __builtin_amdgcn_mfma_f32_16x16x32_bf16(wf, a3[ks], a3c, 0, 0, 0);
    }
    __builtin_nontemporal_store(a3c, reinterpret_cast<f32x4*>(out + orow + 16*t + 4*g));
  }
}

// ---------------- launcher ----------------
extern "C" void kernel_launch(void* const* d_in, const int* in_sizes, int n_in,
                              void* d_out, int out_size, void* d_ws, size_t ws_size,
                              hipStream_t stream)
{
  const float* x     = (const float*)d_in[0];
  const float* emb   = (const float*)d_in[1];
  const float* W_num = (const float*)d_in[2];
  const float* b_num = (const float*)d_in[3];
  const float* W_in  = (const float*)d_in[4];
  const float* b_in  = (const float*)d_in[5];
  const float* W1    = (const float*)d_in[6];
  const float* b1    = (const float*)d_in[7];
  const float* W2    = (const float*)d_in[8];
  const float* b2    = (const float*)d_in[9];
  const float* ln_g  = (const float*)d_in[10];
  const float* ln_b  = (const float*)d_in[11];
  const float* W_out = (const float*)d_in[12];
  const float* b_out = (const float*)d_in[13];
  float* out = (float*)d_out;

  char* ws = (char*)d_ws;
  float*    WLf   = (float*)(ws + 0);         // 131072 B
  float*    Bnum  = (float*)(ws + 131072);    //  10752 B
  float*    bfold = (float*)(ws + 141824);    //   1024 B
  uint16_t* tcatp = (uint16_t*)(ws + 142848); // 256000 B
  uint16_t* wl2p  = (uint16_t*)(ws + 398848); //  32768 B
  uint16_t* woutp = (uint16_t*)(ws + 431616); //  32768 B
  uint16_t* a1p   = (uint16_t*)(ws + 464384); //   8192 B
  float*    bf1p  = (float*)(ws + 472576);    //    512 B
  float*    boutp = (float*)(ws + 473088);    //    512 B

  const int nrows = in_sizes[0] / 40;         // 98304
  const int grid  = nrows / 64;               // 1536

  pre1<<<dim3(312), dim3(128), 0, stream>>>(W_num, b_num, W_in, b_in, W1, b1, W2, b2,
                                            W_out, b_out, ln_g, ln_b,
                                            WLf, Bnum, bfold, woutp, boutp);
  pre2<<<dim3(1041), dim3(128), 0, stream>>>(emb, W_in, ln_g, ln_b, WLf, Bnum, bfold,
                                             tcatp, wl2p, bf1p, a1p);
  fused_main<<<dim3(grid), dim3(256), 0, stream>>>(x, tcatp, a1p, wl2p, woutp,
                                                   bf1p, boutp, out);
}

// Round 5
// 105.777 us; speedup vs baseline: 3.3455x; 2.8505x over previous
//
#include <hip/hip_runtime.h>
#include <hip/hip_bf16.h>
#include <stdint.h>
#include <stddef.h>

// ---------------------------------------------------------------------------
// FixedEmbedderNN — all-linear fold + transposed-MFMA pipeline.
//   WL_i   = W1[i]@W2[i];  bfold_i = b1[i]@W2[i]+b2[i]
//   Tcat1[f][c] = emb[f][c] @ W_in_f @ WL_0      (bf16, column-PERMUTED store)
//   A1[k][:]    = numeric fold rows (k=0..19), k=20 = const base (+bfold_0)
//   LN gamma/beta folded into downstream weights.
// Round-5: round-2's proven code shape (no spills) + line-optimal tcat
// permutation: col 16t+4g+r stored at pos (t>>1)*32 + g*8 + (t&1)*4 + r, so
// the 4 lanes (g) of a row read ONE contiguous 64B line per instruction
// (lane off g*16, instr q steps +64B). In-register uint4 contents identical
// to round 2 (t=2q,2q+1 pairs) -> same CONS mapping, downstream unchanged.
// Per-wave x staging (wave stages its own 16 rows) -> no __syncthreads.
// ---------------------------------------------------------------------------

typedef __attribute__((ext_vector_type(8))) short short8;
typedef __attribute__((ext_vector_type(4))) float f32x4;
typedef __attribute__((ext_vector_type(2))) uint32_t uint32x2;

#define LN_EPS 1e-5f

__device__ __forceinline__ float bflo(uint32_t u){ union{uint32_t u;float f;} c; c.u = u<<16; return c.f; }
__device__ __forceinline__ float bfhi(uint32_t u){ union{uint32_t u;float f;} c; c.u = u&0xffff0000u; return c.f; }
__device__ __forceinline__ uint16_t f2bf(float f){
  union{ __hip_bfloat16 h; uint16_t u; } c; c.h = __float2bfloat16(f); return c.u;
}
__device__ __forceinline__ uint32_t pkbf(float lo, float hi){
  return (uint32_t)f2bf(lo) | ((uint32_t)f2bf(hi)<<16);
}

// ---------------- precompute kernel 1 (no deps) ----------------
__global__ __launch_bounds__(128) void pre1(
    const float* __restrict__ W_num, const float* __restrict__ b_num,
    const float* __restrict__ W_in,  const float* __restrict__ b_in,
    const float* __restrict__ W1,    const float* __restrict__ b1,
    const float* __restrict__ W2,    const float* __restrict__ b2,
    const float* __restrict__ W_out, const float* __restrict__ b_out,
    const float* __restrict__ ln_g,  const float* __restrict__ ln_b,
    float* __restrict__ WLf,    // [2][128][128]
    float* __restrict__ Bnum,   // [21][128]
    float* __restrict__ bfold,  // [2][128]
    uint16_t* __restrict__ woutp, // Wout' transposed pack [(t*4+ks)*64+lane][8]
    float* __restrict__ boutp)    // bout' permuted [g*32+t*4+r]
{
  const int b = blockIdx.x, j = threadIdx.x;
  if (b < 256) {                       // WL = W1@W2 per layer
    const int l = b >> 7, k = b & 127;
    const float* w1r = W1 + (l*128 + k)*256;
    const float* w2  = W2 + l*256*128;
    float s = 0.f;
    for (int m = 0; m < 256; m++) s = fmaf(w1r[m], w2[m*128 + j], s);
    WLf[(l*128 + k)*128 + j] = s;
  } else if (b < 277) {                // Bnum rows
    const int r = b - 256;
    if (r < 20) {
      const float* wn = W_num + r*32;
      const float* wi = W_in + (size_t)(20 + r)*32*128;
      float s = 0.f;
      for (int e = 0; e < 32; e++) s = fmaf(wn[e], wi[e*128 + j], s);
      Bnum[r*128 + j] = s;
    } else {
      float s = b_in[j];
      for (int f = 0; f < 20; f++) {
        const float* bn = b_num + f*32;
        const float* wi = W_in + (size_t)(20 + f)*32*128;
        for (int e = 0; e < 32; e++) s = fmaf(bn[e], wi[e*128 + j], s);
      }
      Bnum[20*128 + j] = s;
    }
  } else if (b < 279) {                // bfold = b1@W2 + b2
    const int l = b - 277;
    const float* b1r = b1 + l*256;
    const float* w2  = W2 + l*256*128;
    float s = b2[l*128 + j];
    for (int k = 0; k < 256; k++) s = fmaf(b1r[k], w2[k*128 + j], s);
    bfold[l*128 + j] = s;
  } else if (b < 311) {                // woutp: Wout' = diag(g1)@W_out, transposed A-pack
    const int p = b - 279, t = p >> 2, ks = p & 3;
    const int lane = j & 63, rep = j >> 6;
    const int col = 16*t + (lane & 15);
    for (int ii = 0; ii < 4; ii++) {
      const int i = rep*4 + ii;
      const int k = 32*ks + 8*(lane >> 4) + i;
      woutp[((t*4 + ks)*64 + lane)*8 + i] = f2bf(ln_g[128 + k] * W_out[k*128 + col]);
    }
  } else {                             // boutp (permuted): b1n@W_out + b_out
    const int t = (j >> 2) & 7, g = j >> 5, r = j & 3;
    const int col = 16*t + 4*g + r;
    float s = b_out[col];
    for (int k = 0; k < 128; k++) s = fmaf(ln_b[128 + k], W_out[k*128 + col], s);
    boutp[j] = s;
  }
}

// ---------------- precompute kernel 2 (depends on pre1) ----------------
__global__ __launch_bounds__(128) void pre2(
    const float* __restrict__ emb, const float* __restrict__ W_in,
    const float* __restrict__ ln_g, const float* __restrict__ ln_b,
    const float* __restrict__ WLf, const float* __restrict__ Bnum,
    const float* __restrict__ bfold,
    uint16_t* __restrict__ tcatp, // [20][50][128] bf16, line-optimal permuted cols
    uint16_t* __restrict__ wl2p,  // WL1' transposed pack
    float* __restrict__ bf1p,     // bf1' permuted
    uint16_t* __restrict__ a1p)   // A1^T A-frag pack [t*64+lane][8]
{
  const int b = blockIdx.x, j = threadIdx.x;
  __shared__ float sh[128];
  if (b < 1000) {                      // Tcat1 = emb@W_in_slice@WL_0, permuted store
    const int f = b / 50, c = b % 50;
    const float* e  = emb + (f*50 + c)*32;
    const float* wi = W_in + (size_t)f*32*128;
    float s = 0.f;
    for (int k = 0; k < 32; k++) s = fmaf(e[k], wi[k*128 + j], s);
    sh[j] = s;
    __syncthreads();
    float s2 = 0.f;
    for (int k = 0; k < 128; k++) s2 = fmaf(sh[k], WLf[k*128 + j], s2);
    // col j = 16t+4g+r  ->  pos = (t>>1)*32 + g*8 + (t&1)*4 + r  (line-optimal)
    const int t = j >> 4, g = (j >> 2) & 3, r = j & 3;
    const int pos = ((t >> 1) << 5) | (g << 3) | ((t & 1) << 2) | r;
    tcatp[(f*50 + c)*128 + pos] = f2bf(s2);
  } else if (b < 1032) {               // wl2p: WL1' = diag(g0)@WL_1, transposed A-pack
    const int p = b - 1000, t = p >> 2, ks = p & 3;
    const int lane = j & 63, rep = j >> 6;
    const int col = 16*t + (lane & 15);
    const float* wl1 = WLf + 16384;
    for (int ii = 0; ii < 4; ii++) {
      const int i = rep*4 + ii;
      const int k = 32*ks + 8*(lane >> 4) + i;
      wl2p[((t*4 + ks)*64 + lane)*8 + i] = f2bf(ln_g[k] * wl1[k*128 + col]);
    }
  } else if (b == 1032) {              // bf1p (permuted): b0@WL_1 + bfold_1
    const int t = (j >> 2) & 7, g = j >> 5, r = j & 3;
    const int col = 16*t + 4*g + r;
    const float* wl1 = WLf + 16384;
    float s = bfold[128 + col];
    for (int k = 0; k < 128; k++) s = fmaf(ln_b[k], wl1[k*128 + col], s);
    bf1p[j] = s;
  } else {                             // a1p: A1[k][col] = Bnum[k]@WL_0 (+bfold0 @k==20)
    const int t = b - 1033;
    const int lane = j & 63, rep = j >> 6;
    const int col = 16*t + (lane & 15);
    for (int ii = 0; ii < 4; ii++) {
      const int i = rep*4 + ii;
      const int k = 8*(lane >> 4) + i;
      float v = 0.f;
      if (k <= 20) {
        if (k == 20) v = bfold[col];
        for (int m = 0; m < 128; m++) v = fmaf(Bnum[k*128 + m], WLf[m*128 + col], v);
      }
      a1p[(t*64 + lane)*8 + i] = f2bf(v);
    }
  }
}

// ---------------- main fused kernel ----------------
// block = 256 thr (4 waves); wave owns 16 rows; block tile = 64 rows.
// Waves fully independent: per-wave x staging + per-wave hbuf, no __syncthreads.
__global__ __launch_bounds__(256, 4) void fused_main(
    const float* __restrict__ x,
    const uint16_t* __restrict__ tcatp,
    const uint16_t* __restrict__ a1p,
    const uint16_t* __restrict__ wl2p,
    const uint16_t* __restrict__ woutp,
    const float* __restrict__ bf1p,
    const float* __restrict__ boutp,
    float* __restrict__ out)
{
  __shared__ float xs[64*41];                        // x tile (stride 41: conflict-free)
  __shared__ __align__(16) uint16_t hbuf[4*16*136];  // per-wave 16x128 bf16, stride 136
  const int tid = threadIdx.x, lane = tid & 63, w = tid >> 6;
  const int g = lane >> 4, c16 = lane & 15;

  // per-wave stage of this wave's own 16 rows (16*40 = 640 floats, coalesced)
  {
    const float* xsrc = x + ((size_t)blockIdx.x*64 + w*16)*40;
    float* xw = xs + w*16*41;
    #pragma unroll
    for (int k = 0; k < 10; k++) {
      const int i = k*64 + lane;
      xw[(i/40)*41 + (i%40)] = xsrc[i];
    }
  }
  asm volatile("s_waitcnt lgkmcnt(0)" ::: "memory");

  const float* xr = xs + (w*16 + c16)*41;        // this lane's row
  uint16_t* hb = hbuf + w*16*136;                // per-wave private

  // ---- numeric part via MFMA: acc[t] (lane owns row c16, cols 16t+4g+r) ----
  short8 xf;
  #pragma unroll
  for (int i = 0; i < 8; i++) {
    const int k = 8*g + i;
    float v = (k < 20) ? xr[20 + k] : (k == 20 ? 1.0f : 0.0f);
    ((uint16_t*)&xf)[i] = f2bf(v);               // ints<50 + {0,1}: exact in bf16
  }
  f32x4 acc[8];
  #pragma unroll
  for (int t = 0; t < 8; t++) {
    const short8 af = *reinterpret_cast<const short8*>(a1p + (t*64 + lane)*8);
    acc[t] = __builtin_amdgcn_mfma_f32_16x16x32_bf16(af, xf, (f32x4){0.f,0.f,0.f,0.f}, 0, 0, 0);
  }

  // ---- categorical gather: 1 contiguous 64B line per instruction ----
  // lane reads 16B at (f*50+idx)*256 + q*64 + g*16 ; uint4 q holds t=2q,2q+1
  const char* tcb = (const char*)tcatp + (uint32_t)g*16u;
  #pragma unroll 2
  for (int f = 0; f < 20; f++) {
    const int idx = (int)xr[f];
    const char* p = tcb + (uint32_t)(f*50 + idx)*256u;
    #pragma unroll
    for (int q = 0; q < 4; q++) {
      const uint4 u = *reinterpret_cast<const uint4*>(p + q*64);
      acc[2*q][0]   += bflo(u.x); acc[2*q][1]   += bfhi(u.x);
      acc[2*q][2]   += bflo(u.y); acc[2*q][3]   += bfhi(u.y);
      acc[2*q+1][0] += bflo(u.z); acc[2*q+1][1] += bfhi(u.z);
      acc[2*q+1][2] += bflo(u.w); acc[2*q+1][3] += bfhi(u.w);
    }
  }

  // ---- LN_0 (gamma/beta folded downstream): z1 = (acc-mu)*rs ----
  float s = 0.f;
  #pragma unroll
  for (int t = 0; t < 8; t++) { s += acc[t][0]+acc[t][1]+acc[t][2]+acc[t][3]; }
  s += __shfl_xor(s, 16); s += __shfl_xor(s, 32);
  const float mu = s * (1.f/128.f);
  float qv = 0.f;
  #pragma unroll
  for (int t = 0; t < 8; t++)
    #pragma unroll
    for (int r = 0; r < 4; r++) { const float d = acc[t][r]-mu; qv = fmaf(d, d, qv); }
  qv += __shfl_xor(qv, 16); qv += __shfl_xor(qv, 32);
  const float rs = rsqrtf(qv*(1.f/128.f) + LN_EPS);

  #pragma unroll
  for (int t = 0; t < 8; t++) {
    const uint32x2 v = { pkbf((acc[t][0]-mu)*rs, (acc[t][1]-mu)*rs),
                         pkbf((acc[t][2]-mu)*rs, (acc[t][3]-mu)*rs) };
    *reinterpret_cast<uint32x2*>(hb + c16*136 + 16*t + 4*g) = v;
  }
  asm volatile("s_waitcnt lgkmcnt(0)" ::: "memory");

  // ---- GEMM2' (transposed): acc2 = z1 @ WL1' ----
  short8 a2[4];
  #pragma unroll
  for (int ks = 0; ks < 4; ks++)
    a2[ks] = *reinterpret_cast<const short8*>(hb + c16*136 + 32*ks + 8*g);
  f32x4 acc2[8];
  #pragma unroll
  for (int t = 0; t < 8; t++) {
    acc2[t] = *reinterpret_cast<const f32x4*>(bf1p + g*32 + t*4);  // bias as C-init
    #pragma unroll
    for (int ks = 0; ks < 4; ks++) {
      const short8 wf = *reinterpret_cast<const short8*>(wl2p + ((t*4 + ks)*64 + lane)*8);
      acc2[t] = __builtin_amdgcn_mfma_f32_16x16x32_bf16(wf, a2[ks], acc2[t], 0, 0, 0);
    }
  }

  // ---- LN_1: z2 = (acc2-mu2)*rs2 ----
  float s2 = 0.f;
  #pragma unroll
  for (int t = 0; t < 8; t++) { s2 += acc2[t][0]+acc2[t][1]+acc2[t][2]+acc2[t][3]; }
  s2 += __shfl_xor(s2, 16); s2 += __shfl_xor(s2, 32);
  const float mu2 = s2 * (1.f/128.f);
  float q2 = 0.f;
  #pragma unroll
  for (int t = 0; t < 8; t++)
    #pragma unroll
    for (int r = 0; r < 4; r++) { const float d = acc2[t][r]-mu2; q2 = fmaf(d, d, q2); }
  q2 += __shfl_xor(q2, 16); q2 += __shfl_xor(q2, 32);
  const float rs2 = rsqrtf(q2*(1.f/128.f) + LN_EPS);

  asm volatile("s_waitcnt lgkmcnt(0)" ::: "memory");   // a2 reads done before overwrite
  #pragma unroll
  for (int t = 0; t < 8; t++) {
    const uint32x2 v = { pkbf((acc2[t][0]-mu2)*rs2, (acc2[t][1]-mu2)*rs2),
                         pkbf((acc2[t][2]-mu2)*rs2, (acc2[t][3]-mu2)*rs2) };
    *reinterpret_cast<uint32x2*>(hb + c16*136 + 16*t + 4*g) = v;
  }
  asm volatile("s_waitcnt lgkmcnt(0)" ::: "memory");

  // ---- GEMM3' (transposed): out = z2 @ Wout' + bout' ----
  short8 a3[4];
  #pragma unroll
  for (int ks = 0; ks < 4; ks++)
    a3[ks] = *reinterpret_cast<const short8*>(hb + c16*136 + 32*ks + 8*g);
  const size_t orow = ((size_t)blockIdx.x*64 + w*16 + c16)*128;
  #pragma unroll
  for (int t = 0; t < 8; t++) {
    f32x4 a3c = *reinterpret_cast<const f32x4*>(boutp + g*32 + t*4);  // bias as C-init
    #pragma unroll
    for (int ks = 0; ks < 4; ks++) {
      const short8 wf = *reinterpret_cast<const short8*>(woutp + ((t*4 + ks)*64 + lane)*8);
      a3c = __builtin_amdgcn_mfma_f32_16x16x32_bf16(wf, a3[ks], a3c, 0, 0, 0);
    }
    __builtin_nontemporal_store(a3c, reinterpret_cast<f32x4*>(out + orow + 16*t + 4*g));
  }
}

// ---------------- launcher ----------------
extern "C" void kernel_launch(void* const* d_in, const int* in_sizes, int n_in,
                              void* d_out, int out_size, void* d_ws, size_t ws_size,
                              hipStream_t stream)
{
  const float* x     = (const float*)d_in[0];
  const float* emb   = (const float*)d_in[1];
  const float* W_num = (const float*)d_in[2];
  const float* b_num = (const float*)d_in[3];
  const float* W_in  = (const float*)d_in[4];
  const float* b_in  = (const float*)d_in[5];
  const float* W1    = (const float*)d_in[6];
  const float* b1    = (const float*)d_in[7];
  const float* W2    = (const float*)d_in[8];
  const float* b2    = (const float*)d_in[9];
  const float* ln_g  = (const float*)d_in[10];
  const float* ln_b  = (const float*)d_in[11];
  const float* W_out = (const float*)d_in[12];
  const float* b_out = (const float*)d_in[13];
  float* out = (float*)d_out;

  char* ws = (char*)d_ws;
  float*    WLf   = (float*)(ws + 0);         // 131072 B
  float*    Bnum  = (float*)(ws + 131072);    //  10752 B
  float*    bfold = (float*)(ws + 141824);    //   1024 B
  uint16_t* tcatp = (uint16_t*)(ws + 142848); // 256000 B
  uint16_t* wl2p  = (uint16_t*)(ws + 398848); //  32768 B
  uint16_t* woutp = (uint16_t*)(ws + 431616); //  32768 B
  uint16_t* a1p   = (uint16_t*)(ws + 464384); //   8192 B
  float*    bf1p  = (float*)(ws + 472576);    //    512 B
  float*    boutp = (float*)(ws + 473088);    //    512 B

  const int nrows = in_sizes[0] / 40;         // 98304
  const int grid  = nrows / 64;               // 1536

  pre1<<<dim3(312), dim3(128), 0, stream>>>(W_num, b_num, W_in, b_in, W1, b1, W2, b2,
                                            W_out, b_out, ln_g, ln_b,
                                            WLf, Bnum, bfold, woutp, boutp);
  pre2<<<dim3(1041), dim3(128), 0, stream>>>(emb, W_in, ln_g, ln_b, WLf, Bnum, bfold,
                                             tcatp, wl2p, bf1p, a1p);
  fused_main<<<dim3(grid), dim3(256), 0, stream>>>(x, tcatp, a1p, wl2p, woutp,
                                                   bf1p, boutp, out);
}